// Round 5
// baseline (827.783 us; speedup 1.0000x reference)
//
#include <hip/hip_runtime.h>
#include <hip/hip_bf16.h>

#define IN_CH 64
#define HID 32
#define HEADS 4
#define OUT_CH 6
#define NEG_SLOPE 0.2f

// ---------------- preprocessing: build dst-CSR ----------------

// 4 edges per thread, int4 loads, batched atomics for latency hiding
__global__ void hist_kernel(const int* __restrict__ ei, int E, int N, int* __restrict__ cnt) {
    int t = blockIdx.x * blockDim.x + threadIdx.x;
    int e0 = t * 4;
    int EN = E + N;
    if (e0 >= EN) return;
    int d[4];
    if (((E & 3) == 0) && (e0 + 3 < E)) {
        int4 dv = *reinterpret_cast<const int4*>(ei + E + e0);
        d[0] = dv.x; d[1] = dv.y; d[2] = dv.z; d[3] = dv.w;
    } else {
#pragma unroll
        for (int k = 0; k < 4; ++k) {
            int e = e0 + k;
            d[k] = (e < E) ? ei[E + e] : (e < EN ? e - E : -1);
        }
    }
#pragma unroll
    for (int k = 0; k < 4; ++k)
        if (d[k] >= 0) atomicAdd(&cnt[d[k]], 1);
}

// ---- multi-block scan: partial sums -> scan sums -> apply ----
#define SCAN_ELEMS 1024

__global__ __launch_bounds__(256) void scan_partial(const int* __restrict__ cnt, int N,
                                                    int* __restrict__ blocksum) {
    __shared__ int red[256];
    int t = threadIdx.x;
    int b0 = blockIdx.x * SCAN_ELEMS;
    int sum = 0;
#pragma unroll
    for (int i = 0; i < SCAN_ELEMS / 256; ++i) {
        int g = b0 + t + i * 256;
        sum += (g < N) ? cnt[g] : 0;
    }
    red[t] = sum;
    __syncthreads();
    for (int off = 128; off; off >>= 1) {
        if (t < off) red[t] += red[t + off];
        __syncthreads();
    }
    if (t == 0) blocksum[blockIdx.x] = red[0];
}

__global__ __launch_bounds__(256) void scan_sums(int* __restrict__ blocksum, int nb) {
    __shared__ int tmp[256];
    int t = threadIdx.x;
    int chunk = (nb + 255) >> 8;
    int s0 = t * chunk, s1 = min(s0 + chunk, nb);
    int sum = 0;
    for (int i = s0; i < s1; ++i) sum += blocksum[i];
    tmp[t] = sum;
    __syncthreads();
    for (int off = 1; off < 256; off <<= 1) {
        int v = (t >= off) ? tmp[t - off] : 0;
        __syncthreads();
        tmp[t] += v;
        __syncthreads();
    }
    int run = (t == 0) ? 0 : tmp[t - 1];
    for (int i = s0; i < s1; ++i) {
        int c = blocksum[i];
        blocksum[i] = run;
        run += c;
    }
}

__global__ __launch_bounds__(256) void scan_apply(const int* __restrict__ cnt, int N, int total,
                                                  const int* __restrict__ blocksum,
                                                  int* __restrict__ row_start,
                                                  int* __restrict__ cursor) {
    __shared__ int tmp[256];
    int t = threadIdx.x;
    int g = blockIdx.x * SCAN_ELEMS + t * 4;
    int4 c = make_int4(0, 0, 0, 0);
    if (g + 3 < N) {
        c = *reinterpret_cast<const int4*>(cnt + g);
    } else {
        if (g + 0 < N) c.x = cnt[g + 0];
        if (g + 1 < N) c.y = cnt[g + 1];
        if (g + 2 < N) c.z = cnt[g + 2];
        if (g + 3 < N) c.w = cnt[g + 3];
    }
    tmp[t] = c.x + c.y + c.z + c.w;
    __syncthreads();
    for (int off = 1; off < 256; off <<= 1) {
        int v = (t >= off) ? tmp[t - off] : 0;
        __syncthreads();
        tmp[t] += v;
        __syncthreads();
    }
    int4 rs;
    rs.x = blocksum[blockIdx.x] + ((t == 0) ? 0 : tmp[t - 1]);
    rs.y = rs.x + c.x;
    rs.z = rs.y + c.y;
    rs.w = rs.z + c.z;
    if (g + 3 < N) {
        *reinterpret_cast<int4*>(row_start + g) = rs;
        *reinterpret_cast<int4*>(cursor + g) = rs;
    } else {
        if (g + 0 < N) { row_start[g + 0] = rs.x; cursor[g + 0] = rs.x; }
        if (g + 1 < N) { row_start[g + 1] = rs.y; cursor[g + 1] = rs.y; }
        if (g + 2 < N) { row_start[g + 2] = rs.z; cursor[g + 2] = rs.z; }
        if (g + 3 < N) { row_start[g + 3] = rs.w; cursor[g + 3] = rs.w; }
    }
    if (blockIdx.x == 0 && t == 0) row_start[N] = total;   // total known analytically (E+N)
}

// 4 edges per thread: issue all 4 atomics before the dependent stores
__global__ void scatter_kernel(const int* __restrict__ ei, int E, int N,
                               int* __restrict__ cursor, int* __restrict__ csr_src) {
    int t = blockIdx.x * blockDim.x + threadIdx.x;
    int e0 = t * 4;
    int EN = E + N;
    if (e0 >= EN) return;
    int s[4], d[4];
    if (((E & 3) == 0) && (e0 + 3 < E)) {
        int4 sv = *reinterpret_cast<const int4*>(ei + e0);
        int4 dv = *reinterpret_cast<const int4*>(ei + E + e0);
        s[0] = sv.x; s[1] = sv.y; s[2] = sv.z; s[3] = sv.w;
        d[0] = dv.x; d[1] = dv.y; d[2] = dv.z; d[3] = dv.w;
    } else {
#pragma unroll
        for (int k = 0; k < 4; ++k) {
            int e = e0 + k;
            if (e < E)       { s[k] = ei[e]; d[k] = ei[E + e]; }
            else if (e < EN) { s[k] = e - E; d[k] = s[k]; }
            else             { s[k] = 0; d[k] = -1; }
        }
    }
    int pos[4];
#pragma unroll
    for (int k = 0; k < 4; ++k)
        pos[k] = (d[k] >= 0) ? atomicAdd(&cursor[d[k]], 1) : 0;
#pragma unroll
    for (int k = 0; k < 4; ++k)
        if (d[k] >= 0) csr_src[pos[k]] = s[k];
}

// ------- GEMM: C[N][128] = A[N][K] @ W[K][128], fused als/ald epilogue -------

#define BM 32
#define BKK 32

__global__ __launch_bounds__(256) void gemm128_kernel(const float* __restrict__ A,
                                                      const float* __restrict__ W,
                                                      const float* __restrict__ avs,
                                                      const float* __restrict__ avd,
                                                      float* __restrict__ C,
                                                      float* __restrict__ als,
                                                      float* __restrict__ ald,
                                                      int N, int K) {
    __shared__ float xs[BM][BKK + 1];
    __shared__ float ws[BKK][128];
    __shared__ float red_s[BM][9];
    __shared__ float red_d[BM][9];
    int tid = threadIdx.x;
    int r  = tid & 31;
    int cg = tid >> 5;            // 0..7, 16-col group
    int row0 = blockIdx.x * BM;

    float acc[16];
#pragma unroll
    for (int j = 0; j < 16; ++j) acc[j] = 0.f;

    for (int kk = 0; kk < K; kk += BKK) {
        {   // x tile: 32 rows x 32 cols, 4 floats/thread
            int lr = tid >> 3, lc = (tid & 7) * 4;
            int gr = row0 + lr;
            float4 v = make_float4(0.f, 0.f, 0.f, 0.f);
            if (gr < N) v = *reinterpret_cast<const float4*>(A + (size_t)gr * K + kk + lc);
            xs[lr][lc + 0] = v.x; xs[lr][lc + 1] = v.y;
            xs[lr][lc + 2] = v.z; xs[lr][lc + 3] = v.w;
        }
        {   // W tile: 32 rows x 128 cols, 16 floats/thread
            int wr = tid >> 3, wc = (tid & 7) * 16;
            const float4* src = reinterpret_cast<const float4*>(W + (size_t)(kk + wr) * 128 + wc);
            float4* dst = reinterpret_cast<float4*>(&ws[wr][wc]);
#pragma unroll
            for (int i = 0; i < 4; ++i) dst[i] = src[i];
        }
        __syncthreads();
#pragma unroll 8
        for (int k = 0; k < BKK; ++k) {
            float xv = xs[r][k];
            const float4* wrow = reinterpret_cast<const float4*>(&ws[k][cg * 16]);
#pragma unroll
            for (int q = 0; q < 4; ++q) {
                float4 wv = wrow[q];
                acc[q * 4 + 0] += xv * wv.x;
                acc[q * 4 + 1] += xv * wv.y;
                acc[q * 4 + 2] += xv * wv.z;
                acc[q * 4 + 3] += xv * wv.w;
            }
        }
        __syncthreads();
    }
    int gr = row0 + r;
    if (gr < N) {
        float4* out = reinterpret_cast<float4*>(C + (size_t)gr * 128 + cg * 16);
#pragma unroll
        for (int q = 0; q < 4; ++q)
            out[q] = make_float4(acc[q * 4 + 0], acc[q * 4 + 1], acc[q * 4 + 2], acc[q * 4 + 3]);
    }
    // fused attention-logit partials: als[n][hd] = sum_d h[n][hd][d]*as[hd][d]
    {
        float ps = 0.f, pd = 0.f;
#pragma unroll
        for (int q = 0; q < 16; ++q) {
            float a = acc[q];
            ps += a * avs[cg * 16 + q];
            pd += a * avd[cg * 16 + q];
        }
        red_s[r][cg] = ps;
        red_d[r][cg] = pd;
        __syncthreads();
        if (gr < N) {
            if (cg < 4) {
                als[(size_t)gr * 4 + cg] = red_s[r][2 * cg] + red_s[r][2 * cg + 1];
            } else {
                int hd = cg - 4;
                ald[(size_t)gr * 4 + hd] = red_d[r][2 * hd] + red_d[r][2 * hd + 1];
            }
        }
    }
}

// ---------------- wave-per-node aggregation (layers 0-2) ----------------
// Single pass: softmax shift = self-loop logit (alpha is shift-invariant;
// fp32 exp tolerates |logit-shift| up to ~88 -- ample).
// Gather: lanes 0-31 even edges / 32-63 odd edges, float4 per lane
// -> 1024B (2 rows) per vmem instruction; unroll 4 pairs = 8 edges in flight.

__device__ __forceinline__ float lrelu(float x) { return x > 0.f ? x : NEG_SLOPE * x; }

__global__ __launch_bounds__(256) void agg_kernel(const float* __restrict__ h,
                                                  const float* __restrict__ als4,
                                                  const float* __restrict__ ald4,
                                                  const int* __restrict__ row_start,
                                                  const int* __restrict__ csr_src,
                                                  const float* __restrict__ bias,
                                                  float* __restrict__ xout,
                                                  int N, int applyElu) {
    __shared__ float ex_s[4][256];   // [waveInBlock][edge*4+head]
    __shared__ int   ss_s[4][64];    // [waveInBlock][edge]
    int w = threadIdx.x >> 6;
    int v = blockIdx.x * 4 + w;
    int lane = threadIdx.x & 63;
    if (v >= N) return;
    int base = row_start[v], end = row_start[v + 1];

    float4 aldv4 = *reinterpret_cast<const float4*>(ald4 + (size_t)v * 4);
    float4 alsv4 = *reinterpret_cast<const float4*>(als4 + (size_t)v * 4);
    float4 em4;   // self-loop logit as numeric shift
    em4.x = lrelu(alsv4.x + aldv4.x);
    em4.y = lrelu(alsv4.y + aldv4.y);
    em4.z = lrelu(alsv4.z + aldv4.z);
    em4.w = lrelu(alsv4.w + aldv4.w);

    int half = lane >> 5;          // 0: even edges, 1: odd edges
    int dim4 = (lane & 31) * 4;    // 4-dim group of the 128-dim row
    int hd2  = (lane & 31) >> 3;   // head of this dim group
    const float* hdim = h + dim4;

    float4 sum4 = make_float4(0.f, 0.f, 0.f, 0.f);
    float4 acc  = make_float4(0.f, 0.f, 0.f, 0.f);
    float4 acc2 = make_float4(0.f, 0.f, 0.f, 0.f);

    for (int c = base; c < end; c += 64) {
        int j = c + lane;
        bool valid = j < end;
        int s = valid ? csr_src[j] : 0;
        float4 ex4 = make_float4(0.f, 0.f, 0.f, 0.f);
        if (valid) {
            float4 a = *reinterpret_cast<const float4*>(als4 + (size_t)s * 4);
            ex4.x = __expf(lrelu(a.x + aldv4.x) - em4.x);
            ex4.y = __expf(lrelu(a.y + aldv4.y) - em4.y);
            ex4.z = __expf(lrelu(a.z + aldv4.z) - em4.z);
            ex4.w = __expf(lrelu(a.w + aldv4.w) - em4.w);
            sum4.x += ex4.x; sum4.y += ex4.y; sum4.z += ex4.z; sum4.w += ex4.w;
        }
        *reinterpret_cast<float4*>(&ex_s[w][lane * 4]) = ex4;
        ss_s[w][lane] = s;
        int cnt = end - c; if (cnt > 64) cnt = 64;
        int t = 0;
        for (; t + 7 < cnt; t += 8) {   // 4 pair-iters, 4 gathers in flight/lane
            int i0 = t + half, i1 = t + 2 + half, i2 = t + 4 + half, i3 = t + 6 + half;
            int s0 = ss_s[w][i0], s1 = ss_s[w][i1], s2 = ss_s[w][i2], s3 = ss_s[w][i3];
            float e0 = ex_s[w][i0 * 4 + hd2], e1 = ex_s[w][i1 * 4 + hd2];
            float e2 = ex_s[w][i2 * 4 + hd2], e3 = ex_s[w][i3 * 4 + hd2];
            float4 h0 = *reinterpret_cast<const float4*>(hdim + (size_t)s0 * 128);
            float4 h1 = *reinterpret_cast<const float4*>(hdim + (size_t)s1 * 128);
            float4 h2 = *reinterpret_cast<const float4*>(hdim + (size_t)s2 * 128);
            float4 h3 = *reinterpret_cast<const float4*>(hdim + (size_t)s3 * 128);
            acc.x  += e0 * h0.x; acc.y  += e0 * h0.y; acc.z  += e0 * h0.z; acc.w  += e0 * h0.w;
            acc2.x += e1 * h1.x; acc2.y += e1 * h1.y; acc2.z += e1 * h1.z; acc2.w += e1 * h1.w;
            acc.x  += e2 * h2.x; acc.y  += e2 * h2.y; acc.z  += e2 * h2.z; acc.w  += e2 * h2.w;
            acc2.x += e3 * h3.x; acc2.y += e3 * h3.y; acc2.z += e3 * h3.z; acc2.w += e3 * h3.w;
        }
        for (; t < cnt; t += 2) {       // tail pairs (index cnt holds ex=0 when odd)
            int i0 = t + half;
            int s0 = ss_s[w][i0];
            float e0 = ex_s[w][i0 * 4 + hd2];
            float4 h0 = *reinterpret_cast<const float4*>(hdim + (size_t)s0 * 128);
            acc.x += e0 * h0.x; acc.y += e0 * h0.y; acc.z += e0 * h0.z; acc.w += e0 * h0.w;
        }
    }
    acc.x += acc2.x; acc.y += acc2.y; acc.z += acc2.z; acc.w += acc2.w;
    // merge even/odd halves
    acc.x += __shfl_xor(acc.x, 32);
    acc.y += __shfl_xor(acc.y, 32);
    acc.z += __shfl_xor(acc.z, 32);
    acc.w += __shfl_xor(acc.w, 32);
    // per-head denominator butterfly
#pragma unroll
    for (int off = 32; off; off >>= 1) {
        sum4.x += __shfl_xor(sum4.x, off);
        sum4.y += __shfl_xor(sum4.y, off);
        sum4.z += __shfl_xor(sum4.z, off);
        sum4.w += __shfl_xor(sum4.w, off);
    }
    if (lane < 32) {
        float ssum = (hd2 == 0) ? sum4.x : (hd2 == 1) ? sum4.y : (hd2 == 2) ? sum4.z : sum4.w;
        float inv = 1.0f / (ssum + 1e-16f);
        float4 bv = *reinterpret_cast<const float4*>(bias + dim4);
        float4 o;
        o.x = acc.x * inv + bv.x;
        o.y = acc.y * inv + bv.y;
        o.z = acc.z * inv + bv.z;
        o.w = acc.w * inv + bv.w;
        if (applyElu) {
            o.x = o.x > 0.f ? o.x : expm1f(o.x);
            o.y = o.y > 0.f ? o.y : expm1f(o.y);
            o.z = o.z > 0.f ? o.z : expm1f(o.z);
            o.w = o.w > 0.f ? o.w : expm1f(o.w);
        }
        *reinterpret_cast<float4*>(xout + (size_t)v * 128 + dim4) = o;
    }
}

// ---------------- layer 3: GEMM [N,128]x[128,6] with fused al ----------------

__global__ void gemm3_kernel(const float* __restrict__ x, const float* __restrict__ W,
                             const float* __restrict__ as3, const float* __restrict__ ad3,
                             float* __restrict__ h3, float* __restrict__ als3,
                             float* __restrict__ ald3, int N) {
    int n = blockIdx.x * blockDim.x + threadIdx.x;
    if (n >= N) return;
    float acc[6] = {0.f, 0.f, 0.f, 0.f, 0.f, 0.f};
    const float4* xp = reinterpret_cast<const float4*>(x + (size_t)n * 128);
#pragma unroll 4
    for (int k4 = 0; k4 < 32; ++k4) {
        float4 xv = xp[k4];
        const float* w0 = W + (size_t)(k4 * 4) * 6;
#pragma unroll
        for (int j = 0; j < 6; ++j)
            acc[j] += xv.x * w0[j] + xv.y * w0[6 + j] + xv.z * w0[12 + j] + xv.w * w0[18 + j];
    }
    float s = 0.f, d = 0.f;
#pragma unroll
    for (int j = 0; j < 6; ++j) {
        s += acc[j] * as3[j];
        d += acc[j] * ad3[j];
        h3[(size_t)n * 6 + j] = acc[j];
    }
    als3[n] = s;
    ald3[n] = d;
}

// single pass, self-loop shift, 2 independent edge chains
__global__ void agg3_kernel(const float* __restrict__ h3, const float* __restrict__ als3,
                            const float* __restrict__ ald3, const int* __restrict__ row_start,
                            const int* __restrict__ csr_src, const float* __restrict__ b3,
                            float* __restrict__ out, int N) {
    int v = blockIdx.x * blockDim.x + threadIdx.x;
    if (v >= N) return;
    int base = row_start[v], end = row_start[v + 1];
    float aldv = ald3[v];
    float em = lrelu(als3[v] + aldv);
    float ssum = 0.f;
    float acc[6] = {0.f, 0.f, 0.f, 0.f, 0.f, 0.f};
    float acc2[6] = {0.f, 0.f, 0.f, 0.f, 0.f, 0.f};
    int j = base;
    for (; j + 1 < end; j += 2) {
        int sa = csr_src[j], sb = csr_src[j + 1];
        float ea = __expf(lrelu(als3[sa] + aldv) - em);
        float eb = __expf(lrelu(als3[sb] + aldv) - em);
        ssum += ea + eb;
        const float* ha = h3 + (size_t)sa * 6;
        const float* hb = h3 + (size_t)sb * 6;
#pragma unroll
        for (int q = 0; q < 6; ++q) acc[q] += ea * ha[q];
#pragma unroll
        for (int q = 0; q < 6; ++q) acc2[q] += eb * hb[q];
    }
    if (j < end) {
        int sa = csr_src[j];
        float ea = __expf(lrelu(als3[sa] + aldv) - em);
        ssum += ea;
        const float* ha = h3 + (size_t)sa * 6;
#pragma unroll
        for (int q = 0; q < 6; ++q) acc[q] += ea * ha[q];
    }
    float inv = 1.f / (ssum + 1e-16f);
#pragma unroll
    for (int q = 0; q < 6; ++q) out[(size_t)v * 6 + q] = (acc[q] + acc2[q]) * inv + b3[q];
}

// ---------------- launch ----------------

extern "C" void kernel_launch(void* const* d_in, const int* in_sizes, int n_in,
                              void* d_out, int out_size, void* d_ws, size_t ws_size,
                              hipStream_t stream) {
    const float* x    = (const float*)d_in[0];
    const int*   ei   = (const int*)d_in[1];
    const float* W0   = (const float*)d_in[3];
    const float* as0  = (const float*)d_in[4];
    const float* ad0  = (const float*)d_in[5];
    const float* b0   = (const float*)d_in[6];
    const float* W1   = (const float*)d_in[7];
    const float* as1  = (const float*)d_in[8];
    const float* ad1  = (const float*)d_in[9];
    const float* b1   = (const float*)d_in[10];
    const float* W2   = (const float*)d_in[11];
    const float* as2  = (const float*)d_in[12];
    const float* ad2  = (const float*)d_in[13];
    const float* b2   = (const float*)d_in[14];
    const float* W3   = (const float*)d_in[15];
    const float* as3  = (const float*)d_in[16];
    const float* ad3  = (const float*)d_in[17];
    const float* b3   = (const float*)d_in[18];
    float* out = (float*)d_out;

    int N = in_sizes[0] / IN_CH;
    int E = in_sizes[1] / 2;
    int EN = E + N;

    // workspace layout (256B aligned slices)
    char* p = (char*)d_ws;
    auto alloc = [&](size_t bytes) {
        char* q = p;
        p += (bytes + 255) & ~(size_t)255;
        return q;
    };
    float* hbuf = (float*)alloc((size_t)N * 128 * 4);
    float* xA   = (float*)alloc((size_t)N * 128 * 4);
    float* xB   = (float*)alloc((size_t)N * 128 * 4);
    float* als  = (float*)alloc((size_t)N * 4 * 4);
    float* ald  = (float*)alloc((size_t)N * 4 * 4);
    float* h3   = (float*)alloc((size_t)N * 6 * 4);
    float* als3 = (float*)alloc((size_t)N * 4);
    float* ald3 = (float*)alloc((size_t)N * 4);
    int* row_start = (int*)alloc((size_t)(N + 1) * 4);
    int* cursor    = (int*)alloc((size_t)N * 4);
    int* csr_src   = (int*)alloc((size_t)EN * 4);
    int* blocksum  = (int*)alloc((size_t)4096 * 4);
    (void)ws_size; (void)n_in; (void)out_size;

    // ---- build CSR by dst ----
    hipMemsetAsync(cursor, 0, (size_t)N * 4, stream);
    int ethreads = (EN + 3) / 4;
    hist_kernel<<<(ethreads + 255) / 256, 256, 0, stream>>>(ei, E, N, cursor);
    int nb = (N + SCAN_ELEMS - 1) / SCAN_ELEMS;
    scan_partial<<<nb, 256, 0, stream>>>(cursor, N, blocksum);
    scan_sums<<<1, 256, 0, stream>>>(blocksum, nb);
    scan_apply<<<nb, 256, 0, stream>>>(cursor, N, EN, blocksum, row_start, cursor);
    scatter_kernel<<<(ethreads + 255) / 256, 256, 0, stream>>>(ei, E, N, cursor, csr_src);

    int gemm_grid = (N + BM - 1) / BM;
    int agg_grid  = (N + 3) / 4;      // 4 waves/block, 1 wave/node
    int n_grid    = (N + 255) / 256;

    // ---- layer 0: 64 -> 4x32, ELU ----
    gemm128_kernel<<<gemm_grid, 256, 0, stream>>>(x, W0, as0, ad0, hbuf, als, ald, N, 64);
    agg_kernel<<<agg_grid, 256, 0, stream>>>(hbuf, als, ald, row_start, csr_src, b0, xA, N, 1);

    // ---- layer 1 ----
    gemm128_kernel<<<gemm_grid, 256, 0, stream>>>(xA, W1, as1, ad1, hbuf, als, ald, N, 128);
    agg_kernel<<<agg_grid, 256, 0, stream>>>(hbuf, als, ald, row_start, csr_src, b1, xB, N, 1);

    // ---- layer 2 ----
    gemm128_kernel<<<gemm_grid, 256, 0, stream>>>(xB, W2, as2, ad2, hbuf, als, ald, N, 128);
    agg_kernel<<<agg_grid, 256, 0, stream>>>(hbuf, als, ald, row_start, csr_src, b2, xA, N, 1);

    // ---- layer 3: 128 -> 6, 1 head, no ELU ----
    gemm3_kernel<<<n_grid, 256, 0, stream>>>(xA, W3, as3, ad3, h3, als3, ald3, N);
    agg3_kernel<<<n_grid, 256, 0, stream>>>(h3, als3, ald3, row_start, csr_src, b3, out, N);
}

// Round 6
// 807.894 us; speedup vs baseline: 1.0246x; 1.0246x over previous
//
#include <hip/hip_runtime.h>
#include <hip/hip_bf16.h>

#define IN_CH 64
#define HID 32
#define HEADS 4
#define OUT_CH 6
#define NEG_SLOPE 0.2f

// ---------------- preprocessing: build dst-CSR ----------------

// 4 edges per thread, int4 loads, batched atomics for latency hiding
__global__ void hist_kernel(const int* __restrict__ ei, int E, int N, int* __restrict__ cnt) {
    int t = blockIdx.x * blockDim.x + threadIdx.x;
    int e0 = t * 4;
    int EN = E + N;
    if (e0 >= EN) return;
    int d[4];
    if (((E & 3) == 0) && (e0 + 3 < E)) {
        int4 dv = *reinterpret_cast<const int4*>(ei + E + e0);
        d[0] = dv.x; d[1] = dv.y; d[2] = dv.z; d[3] = dv.w;
    } else {
#pragma unroll
        for (int k = 0; k < 4; ++k) {
            int e = e0 + k;
            d[k] = (e < E) ? ei[E + e] : (e < EN ? e - E : -1);
        }
    }
#pragma unroll
    for (int k = 0; k < 4; ++k)
        if (d[k] >= 0) atomicAdd(&cnt[d[k]], 1);
}

// ---- multi-block scan: partial sums -> scan sums -> apply ----
#define SCAN_ELEMS 1024

__global__ __launch_bounds__(256) void scan_partial(const int* __restrict__ cnt, int N,
                                                    int* __restrict__ blocksum) {
    __shared__ int red[256];
    int t = threadIdx.x;
    int b0 = blockIdx.x * SCAN_ELEMS;
    int sum = 0;
#pragma unroll
    for (int i = 0; i < SCAN_ELEMS / 256; ++i) {
        int g = b0 + t + i * 256;
        sum += (g < N) ? cnt[g] : 0;
    }
    red[t] = sum;
    __syncthreads();
    for (int off = 128; off; off >>= 1) {
        if (t < off) red[t] += red[t + off];
        __syncthreads();
    }
    if (t == 0) blocksum[blockIdx.x] = red[0];
}

__global__ __launch_bounds__(256) void scan_sums(int* __restrict__ blocksum, int nb) {
    __shared__ int tmp[256];
    int t = threadIdx.x;
    int chunk = (nb + 255) >> 8;
    int s0 = t * chunk, s1 = min(s0 + chunk, nb);
    int sum = 0;
    for (int i = s0; i < s1; ++i) sum += blocksum[i];
    tmp[t] = sum;
    __syncthreads();
    for (int off = 1; off < 256; off <<= 1) {
        int v = (t >= off) ? tmp[t - off] : 0;
        __syncthreads();
        tmp[t] += v;
        __syncthreads();
    }
    int run = (t == 0) ? 0 : tmp[t - 1];
    for (int i = s0; i < s1; ++i) {
        int c = blocksum[i];
        blocksum[i] = run;
        run += c;
    }
}

__global__ __launch_bounds__(256) void scan_apply(const int* __restrict__ cnt, int N, int total,
                                                  const int* __restrict__ blocksum,
                                                  int* __restrict__ row_start,
                                                  int* __restrict__ cursor) {
    __shared__ int tmp[256];
    int t = threadIdx.x;
    int g = blockIdx.x * SCAN_ELEMS + t * 4;
    int4 c = make_int4(0, 0, 0, 0);
    if (g + 3 < N) {
        c = *reinterpret_cast<const int4*>(cnt + g);
    } else {
        if (g + 0 < N) c.x = cnt[g + 0];
        if (g + 1 < N) c.y = cnt[g + 1];
        if (g + 2 < N) c.z = cnt[g + 2];
        if (g + 3 < N) c.w = cnt[g + 3];
    }
    tmp[t] = c.x + c.y + c.z + c.w;
    __syncthreads();
    for (int off = 1; off < 256; off <<= 1) {
        int v = (t >= off) ? tmp[t - off] : 0;
        __syncthreads();
        tmp[t] += v;
        __syncthreads();
    }
    int4 rs;
    rs.x = blocksum[blockIdx.x] + ((t == 0) ? 0 : tmp[t - 1]);
    rs.y = rs.x + c.x;
    rs.z = rs.y + c.y;
    rs.w = rs.z + c.z;
    if (g + 3 < N) {
        *reinterpret_cast<int4*>(row_start + g) = rs;
        *reinterpret_cast<int4*>(cursor + g) = rs;
    } else {
        if (g + 0 < N) { row_start[g + 0] = rs.x; cursor[g + 0] = rs.x; }
        if (g + 1 < N) { row_start[g + 1] = rs.y; cursor[g + 1] = rs.y; }
        if (g + 2 < N) { row_start[g + 2] = rs.z; cursor[g + 2] = rs.z; }
        if (g + 3 < N) { row_start[g + 3] = rs.w; cursor[g + 3] = rs.w; }
    }
    if (blockIdx.x == 0 && t == 0) row_start[N] = total;   // total known analytically (E+N)
}

// 4 edges per thread: issue all 4 atomics before the dependent stores
__global__ void scatter_kernel(const int* __restrict__ ei, int E, int N,
                               int* __restrict__ cursor, int* __restrict__ csr_src) {
    int t = blockIdx.x * blockDim.x + threadIdx.x;
    int e0 = t * 4;
    int EN = E + N;
    if (e0 >= EN) return;
    int s[4], d[4];
    if (((E & 3) == 0) && (e0 + 3 < E)) {
        int4 sv = *reinterpret_cast<const int4*>(ei + e0);
        int4 dv = *reinterpret_cast<const int4*>(ei + E + e0);
        s[0] = sv.x; s[1] = sv.y; s[2] = sv.z; s[3] = sv.w;
        d[0] = dv.x; d[1] = dv.y; d[2] = dv.z; d[3] = dv.w;
    } else {
#pragma unroll
        for (int k = 0; k < 4; ++k) {
            int e = e0 + k;
            if (e < E)       { s[k] = ei[e]; d[k] = ei[E + e]; }
            else if (e < EN) { s[k] = e - E; d[k] = s[k]; }
            else             { s[k] = 0; d[k] = -1; }
        }
    }
    int pos[4];
#pragma unroll
    for (int k = 0; k < 4; ++k)
        pos[k] = (d[k] >= 0) ? atomicAdd(&cursor[d[k]], 1) : 0;
#pragma unroll
    for (int k = 0; k < 4; ++k)
        if (d[k] >= 0) csr_src[pos[k]] = s[k];
}

// ------- GEMM: C[N][128] = A[N][K] @ W[K][128], fused als/ald epilogue -------

#define BM 32
#define BKK 32

__global__ __launch_bounds__(256) void gemm128_kernel(const float* __restrict__ A,
                                                      const float* __restrict__ W,
                                                      const float* __restrict__ avs,
                                                      const float* __restrict__ avd,
                                                      float* __restrict__ C,
                                                      float* __restrict__ als,
                                                      float* __restrict__ ald,
                                                      int N, int K) {
    __shared__ float xs[BM][BKK + 1];
    __shared__ float ws[BKK][128];
    __shared__ float red_s[BM][9];
    __shared__ float red_d[BM][9];
    int tid = threadIdx.x;
    int r  = tid & 31;
    int cg = tid >> 5;            // 0..7, 16-col group
    int row0 = blockIdx.x * BM;

    float acc[16];
#pragma unroll
    for (int j = 0; j < 16; ++j) acc[j] = 0.f;

    for (int kk = 0; kk < K; kk += BKK) {
        {   // x tile: 32 rows x 32 cols, 4 floats/thread
            int lr = tid >> 3, lc = (tid & 7) * 4;
            int gr = row0 + lr;
            float4 v = make_float4(0.f, 0.f, 0.f, 0.f);
            if (gr < N) v = *reinterpret_cast<const float4*>(A + (size_t)gr * K + kk + lc);
            xs[lr][lc + 0] = v.x; xs[lr][lc + 1] = v.y;
            xs[lr][lc + 2] = v.z; xs[lr][lc + 3] = v.w;
        }
        {   // W tile: 32 rows x 128 cols, 16 floats/thread
            int wr = tid >> 3, wc = (tid & 7) * 16;
            const float4* src = reinterpret_cast<const float4*>(W + (size_t)(kk + wr) * 128 + wc);
            float4* dst = reinterpret_cast<float4*>(&ws[wr][wc]);
#pragma unroll
            for (int i = 0; i < 4; ++i) dst[i] = src[i];
        }
        __syncthreads();
#pragma unroll 8
        for (int k = 0; k < BKK; ++k) {
            float xv = xs[r][k];
            const float4* wrow = reinterpret_cast<const float4*>(&ws[k][cg * 16]);
#pragma unroll
            for (int q = 0; q < 4; ++q) {
                float4 wv = wrow[q];
                acc[q * 4 + 0] += xv * wv.x;
                acc[q * 4 + 1] += xv * wv.y;
                acc[q * 4 + 2] += xv * wv.z;
                acc[q * 4 + 3] += xv * wv.w;
            }
        }
        __syncthreads();
    }
    int gr = row0 + r;
    if (gr < N) {
        float4* out = reinterpret_cast<float4*>(C + (size_t)gr * 128 + cg * 16);
#pragma unroll
        for (int q = 0; q < 4; ++q)
            out[q] = make_float4(acc[q * 4 + 0], acc[q * 4 + 1], acc[q * 4 + 2], acc[q * 4 + 3]);
    }
    // fused attention-logit partials: als[n][hd] = sum_d h[n][hd][d]*as[hd][d]
    {
        float ps = 0.f, pd = 0.f;
#pragma unroll
        for (int q = 0; q < 16; ++q) {
            float a = acc[q];
            ps += a * avs[cg * 16 + q];
            pd += a * avd[cg * 16 + q];
        }
        red_s[r][cg] = ps;
        red_d[r][cg] = pd;
        __syncthreads();
        if (gr < N) {
            if (cg < 4) {
                als[(size_t)gr * 4 + cg] = red_s[r][2 * cg] + red_s[r][2 * cg + 1];
            } else {
                int hd = cg - 4;
                ald[(size_t)gr * 4 + hd] = red_d[r][2 * hd] + red_d[r][2 * hd + 1];
            }
        }
    }
}

// ---------------- wave-per-node aggregation (layers 0-2) ----------------
// Flat single-stream loop, no LDS, no phases. All 32 lanes of a half-wave
// process the same edge (lane = dim4 slice); csr_src / als loads are
// uniform-address broadcasts (1 request), exp computed redundantly (VALU
// has headroom). Unroll x4 -> 12 independent loads in flight per lane.
// Softmax shift = self-loop logit (shift-invariance; fp32 exp range ample).

__device__ __forceinline__ float lrelu(float x) { return x > 0.f ? x : NEG_SLOPE * x; }

__global__ __launch_bounds__(256) void agg_kernel(const float* __restrict__ h,
                                                  const float* __restrict__ als4,
                                                  const float* __restrict__ ald4,
                                                  const int* __restrict__ row_start,
                                                  const int* __restrict__ csr_src,
                                                  const float* __restrict__ bias,
                                                  float* __restrict__ xout,
                                                  int N, int applyElu) {
    int v = (int)((blockIdx.x * blockDim.x + threadIdx.x) >> 6);
    int lane = threadIdx.x & 63;
    if (v >= N) return;
    int base = row_start[v], end = row_start[v + 1];

    int half = lane >> 5;          // 0: even edges, 1: odd edges
    int dim4 = (lane & 31) * 4;    // 4-dim slice of the 128-dim row
    int hd2  = (lane & 31) >> 3;   // head of this slice

    float aldh = ald4[(size_t)v * 4 + hd2];
    float alsh = als4[(size_t)v * 4 + hd2];
    float em = lrelu(alsh + aldh);          // self-loop logit as numeric shift
    const float* hdim = h + dim4;
    const float* alsb = als4 + hd2;

    float4 acc  = make_float4(0.f, 0.f, 0.f, 0.f);
    float4 acc2 = make_float4(0.f, 0.f, 0.f, 0.f);
    float ssum = 0.f, ssum2 = 0.f;

    int j = base + half;
    for (; j + 6 < end; j += 8) {   // 4 edges per half per iter
        int s0 = csr_src[j + 0];
        int s1 = csr_src[j + 2];
        int s2 = csr_src[j + 4];
        int s3 = csr_src[j + 6];
        float a0 = alsb[(size_t)s0 * 4];
        float a1 = alsb[(size_t)s1 * 4];
        float a2 = alsb[(size_t)s2 * 4];
        float a3 = alsb[(size_t)s3 * 4];
        float4 h0 = *reinterpret_cast<const float4*>(hdim + (size_t)s0 * 128);
        float4 h1 = *reinterpret_cast<const float4*>(hdim + (size_t)s1 * 128);
        float4 h2 = *reinterpret_cast<const float4*>(hdim + (size_t)s2 * 128);
        float4 h3 = *reinterpret_cast<const float4*>(hdim + (size_t)s3 * 128);
        float e0 = __expf(lrelu(a0 + aldh) - em);
        float e1 = __expf(lrelu(a1 + aldh) - em);
        float e2 = __expf(lrelu(a2 + aldh) - em);
        float e3 = __expf(lrelu(a3 + aldh) - em);
        ssum  += e0 + e2;
        ssum2 += e1 + e3;
        acc.x  += e0 * h0.x; acc.y  += e0 * h0.y; acc.z  += e0 * h0.z; acc.w  += e0 * h0.w;
        acc2.x += e1 * h1.x; acc2.y += e1 * h1.y; acc2.z += e1 * h1.z; acc2.w += e1 * h1.w;
        acc.x  += e2 * h2.x; acc.y  += e2 * h2.y; acc.z  += e2 * h2.z; acc.w  += e2 * h2.w;
        acc2.x += e3 * h3.x; acc2.y += e3 * h3.y; acc2.z += e3 * h3.z; acc2.w += e3 * h3.w;
    }
    for (; j < end; j += 2) {
        int s0 = csr_src[j];
        float a0 = alsb[(size_t)s0 * 4];
        float4 h0 = *reinterpret_cast<const float4*>(hdim + (size_t)s0 * 128);
        float e0 = __expf(lrelu(a0 + aldh) - em);
        ssum += e0;
        acc.x += e0 * h0.x; acc.y += e0 * h0.y; acc.z += e0 * h0.z; acc.w += e0 * h0.w;
    }
    acc.x += acc2.x; acc.y += acc2.y; acc.z += acc2.z; acc.w += acc2.w;
    ssum += ssum2;
    // merge even/odd halves
    acc.x += __shfl_xor(acc.x, 32);
    acc.y += __shfl_xor(acc.y, 32);
    acc.z += __shfl_xor(acc.z, 32);
    acc.w += __shfl_xor(acc.w, 32);
    ssum  += __shfl_xor(ssum, 32);

    if (lane < 32) {
        float inv = 1.0f / (ssum + 1e-16f);
        float4 bv = *reinterpret_cast<const float4*>(bias + dim4);
        float4 o;
        o.x = acc.x * inv + bv.x;
        o.y = acc.y * inv + bv.y;
        o.z = acc.z * inv + bv.z;
        o.w = acc.w * inv + bv.w;
        if (applyElu) {
            o.x = o.x > 0.f ? o.x : expm1f(o.x);
            o.y = o.y > 0.f ? o.y : expm1f(o.y);
            o.z = o.z > 0.f ? o.z : expm1f(o.z);
            o.w = o.w > 0.f ? o.w : expm1f(o.w);
        }
        *reinterpret_cast<float4*>(xout + (size_t)v * 128 + dim4) = o;
    }
}

// ---------------- layer 3: GEMM [N,128]x[128,6] with fused al ----------------

__global__ void gemm3_kernel(const float* __restrict__ x, const float* __restrict__ W,
                             const float* __restrict__ as3, const float* __restrict__ ad3,
                             float* __restrict__ h3, float* __restrict__ als3,
                             float* __restrict__ ald3, int N) {
    int n = blockIdx.x * blockDim.x + threadIdx.x;
    if (n >= N) return;
    float acc[6] = {0.f, 0.f, 0.f, 0.f, 0.f, 0.f};
    const float4* xp = reinterpret_cast<const float4*>(x + (size_t)n * 128);
#pragma unroll 4
    for (int k4 = 0; k4 < 32; ++k4) {
        float4 xv = xp[k4];
        const float* w0 = W + (size_t)(k4 * 4) * 6;
#pragma unroll
        for (int j = 0; j < 6; ++j)
            acc[j] += xv.x * w0[j] + xv.y * w0[6 + j] + xv.z * w0[12 + j] + xv.w * w0[18 + j];
    }
    float s = 0.f, d = 0.f;
#pragma unroll
    for (int j = 0; j < 6; ++j) {
        s += acc[j] * as3[j];
        d += acc[j] * ad3[j];
        h3[(size_t)n * 6 + j] = acc[j];
    }
    als3[n] = s;
    ald3[n] = d;
}

// single pass, self-loop shift, 2 independent edge chains
__global__ void agg3_kernel(const float* __restrict__ h3, const float* __restrict__ als3,
                            const float* __restrict__ ald3, const int* __restrict__ row_start,
                            const int* __restrict__ csr_src, const float* __restrict__ b3,
                            float* __restrict__ out, int N) {
    int v = blockIdx.x * blockDim.x + threadIdx.x;
    if (v >= N) return;
    int base = row_start[v], end = row_start[v + 1];
    float aldv = ald3[v];
    float em = lrelu(als3[v] + aldv);
    float ssum = 0.f;
    float acc[6] = {0.f, 0.f, 0.f, 0.f, 0.f, 0.f};
    float acc2[6] = {0.f, 0.f, 0.f, 0.f, 0.f, 0.f};
    int j = base;
    for (; j + 1 < end; j += 2) {
        int sa = csr_src[j], sb = csr_src[j + 1];
        float ea = __expf(lrelu(als3[sa] + aldv) - em);
        float eb = __expf(lrelu(als3[sb] + aldv) - em);
        ssum += ea + eb;
        const float* ha = h3 + (size_t)sa * 6;
        const float* hb = h3 + (size_t)sb * 6;
#pragma unroll
        for (int q = 0; q < 6; ++q) acc[q] += ea * ha[q];
#pragma unroll
        for (int q = 0; q < 6; ++q) acc2[q] += eb * hb[q];
    }
    if (j < end) {
        int sa = csr_src[j];
        float ea = __expf(lrelu(als3[sa] + aldv) - em);
        ssum += ea;
        const float* ha = h3 + (size_t)sa * 6;
#pragma unroll
        for (int q = 0; q < 6; ++q) acc[q] += ea * ha[q];
    }
    float inv = 1.f / (ssum + 1e-16f);
#pragma unroll
    for (int q = 0; q < 6; ++q) out[(size_t)v * 6 + q] = (acc[q] + acc2[q]) * inv + b3[q];
}

// ---------------- launch ----------------

extern "C" void kernel_launch(void* const* d_in, const int* in_sizes, int n_in,
                              void* d_out, int out_size, void* d_ws, size_t ws_size,
                              hipStream_t stream) {
    const float* x    = (const float*)d_in[0];
    const int*   ei   = (const int*)d_in[1];
    const float* W0   = (const float*)d_in[3];
    const float* as0  = (const float*)d_in[4];
    const float* ad0  = (const float*)d_in[5];
    const float* b0   = (const float*)d_in[6];
    const float* W1   = (const float*)d_in[7];
    const float* as1  = (const float*)d_in[8];
    const float* ad1  = (const float*)d_in[9];
    const float* b1   = (const float*)d_in[10];
    const float* W2   = (const float*)d_in[11];
    const float* as2  = (const float*)d_in[12];
    const float* ad2  = (const float*)d_in[13];
    const float* b2   = (const float*)d_in[14];
    const float* W3   = (const float*)d_in[15];
    const float* as3  = (const float*)d_in[16];
    const float* ad3  = (const float*)d_in[17];
    const float* b3   = (const float*)d_in[18];
    float* out = (float*)d_out;

    int N = in_sizes[0] / IN_CH;
    int E = in_sizes[1] / 2;
    int EN = E + N;

    // workspace layout (256B aligned slices)
    char* p = (char*)d_ws;
    auto alloc = [&](size_t bytes) {
        char* q = p;
        p += (bytes + 255) & ~(size_t)255;
        return q;
    };
    float* hbuf = (float*)alloc((size_t)N * 128 * 4);
    float* xA   = (float*)alloc((size_t)N * 128 * 4);
    float* xB   = (float*)alloc((size_t)N * 128 * 4);
    float* als  = (float*)alloc((size_t)N * 4 * 4);
    float* ald  = (float*)alloc((size_t)N * 4 * 4);
    float* h3   = (float*)alloc((size_t)N * 6 * 4);
    float* als3 = (float*)alloc((size_t)N * 4);
    float* ald3 = (float*)alloc((size_t)N * 4);
    int* row_start = (int*)alloc((size_t)(N + 1) * 4);
    int* cursor    = (int*)alloc((size_t)N * 4);
    int* csr_src   = (int*)alloc((size_t)EN * 4);
    int* blocksum  = (int*)alloc((size_t)4096 * 4);
    (void)ws_size; (void)n_in; (void)out_size;

    // ---- build CSR by dst ----
    hipMemsetAsync(cursor, 0, (size_t)N * 4, stream);
    int ethreads = (EN + 3) / 4;
    hist_kernel<<<(ethreads + 255) / 256, 256, 0, stream>>>(ei, E, N, cursor);
    int nb = (N + SCAN_ELEMS - 1) / SCAN_ELEMS;
    scan_partial<<<nb, 256, 0, stream>>>(cursor, N, blocksum);
    scan_sums<<<1, 256, 0, stream>>>(blocksum, nb);
    scan_apply<<<nb, 256, 0, stream>>>(cursor, N, EN, blocksum, row_start, cursor);
    scatter_kernel<<<(ethreads + 255) / 256, 256, 0, stream>>>(ei, E, N, cursor, csr_src);

    int gemm_grid = (N + BM - 1) / BM;
    int agg_grid  = (N + 3) / 4;      // 4 waves/block, 1 wave/node
    int n_grid    = (N + 255) / 256;

    // ---- layer 0: 64 -> 4x32, ELU ----
    gemm128_kernel<<<gemm_grid, 256, 0, stream>>>(x, W0, as0, ad0, hbuf, als, ald, N, 64);
    agg_kernel<<<agg_grid, 256, 0, stream>>>(hbuf, als, ald, row_start, csr_src, b0, xA, N, 1);

    // ---- layer 1 ----
    gemm128_kernel<<<gemm_grid, 256, 0, stream>>>(xA, W1, as1, ad1, hbuf, als, ald, N, 128);
    agg_kernel<<<agg_grid, 256, 0, stream>>>(hbuf, als, ald, row_start, csr_src, b1, xB, N, 1);

    // ---- layer 2 ----
    gemm128_kernel<<<gemm_grid, 256, 0, stream>>>(xB, W2, as2, ad2, hbuf, als, ald, N, 128);
    agg_kernel<<<agg_grid, 256, 0, stream>>>(hbuf, als, ald, row_start, csr_src, b2, xA, N, 1);

    // ---- layer 3: 128 -> 6, 1 head, no ELU ----
    gemm3_kernel<<<n_grid, 256, 0, stream>>>(xA, W3, as3, ad3, h3, als3, ald3, N);
    agg3_kernel<<<n_grid, 256, 0, stream>>>(h3, als3, ald3, row_start, csr_src, b3, out, N);
}